// Round 1
// 1126.742 us; speedup vs baseline: 1.0266x; 1.0266x over previous
//
#include <hip/hip_runtime.h>
#include <math.h>

// B=64, C=512, S=512, E=257, LK=128, HK=129.
// high_x is dead code in the reference: only low_x = attn(low,low,low)+attn(low,high,low).
//
// Pipeline (all heavy math on MFMA f16):
//  1. build_W: Wt[c][n] f16 = combined rfft+projection weight (512 -> 1028), B-transposed
//  2. build_idt: iDt[n][k] f16 = irfft matrix matching OXh row layout [re264|im264]
//  3. gemm_main (MFMA f16): LHf = relu(x @ W + bias) * S_FOLD, f16 rows [lr|li|hr|hi] (264 pad)
//  4. repack_K: LHf -> Kpack in exact MFMA B-frag order (coalesced attention loads)
//  5. repack_V: LHf low -> Vpack (LDS transpose) in PV B-frag order
//  6. attn (MFMA f16 flash): single-barrier-per-chunk schedule, DPP softmax reduces
//  7. gemm_irfft (MFMA f16): out = OXh @ iDt
//
// ws: LHf 69.2 MB + Kpack 75.5 MB + Vpack 35.7 MB + Wt 1.1 MB + iDt 0.6 MB ~= 182 MB.

#define LD16 1056   // halves per LHf row: [lr 264 | li 264 | hr 264 | hi 264]
#define OXOFF 528   // OXh f16 output written into LHf[row][528..1056): [re 264 | im 264]

typedef __attribute__((ext_vector_type(4))) _Float16 f16x4;
typedef __attribute__((ext_vector_type(8))) _Float16 f16x8;
typedef __attribute__((ext_vector_type(4))) float f32x4;

#define S_FOLD 0.24975653f    // sqrt(1/sqrt(257))
#define INV_S  4.0039005f     // 1/S_FOLD
#define SC512  0.0441941738241592f   // 1/sqrt(512)

// ---------------- build combined rfft+projection weight, B-transposed ----------------
// Wt[c][n], c in [0,1088), n in [0,512). c>=1028 -> 0.
// c<257: low_r; 257..513: low_i; 514..770: high_r; 771..1027: high_i.

__global__ __launch_bounds__(256) void build_W(
    const float* __restrict__ l1r, const float* __restrict__ l1i,
    const float* __restrict__ h1r, const float* __restrict__ h1i,
    _Float16* __restrict__ Wt) {
  int c = blockIdx.x;
  int t = threadIdx.x;
  if (c >= 1028) {
    for (int n = t; n < 512; n += 256) Wt[(size_t)c * 512 + n] = (_Float16)0.0f;
    return;
  }
  __shared__ float Tc[512], Ts[512];
  __shared__ float wr[132], wi[132];
  for (int i = t; i < 512; i += 256) {
    float ang = (float)i * 0.0122718463030851f;  // 2*pi/512
    Tc[i] = cosf(ang);
    Ts[i] = sinf(ang);
  }
  int sub = (c >= 771) ? 3 : (c >= 514) ? 2 : (c >= 257) ? 1 : 0;
  int e = c - sub * 257;
  int Kn = (sub < 2) ? 128 : 129;
  int kb = (sub < 2) ? 0 : 128;
  if (t < Kn) {
    if (sub < 2) { wr[t] = l1r[t * 257 + e]; wi[t] = l1i[t * 257 + e]; }
    else         { wr[t] = h1r[t * 257 + e]; wi[t] = h1i[t * 257 + e]; }
  }
  __syncthreads();
  bool imag_out = (sub & 1);
  for (int n = t; n < 512; n += 256) {
    float acc = 0.f;
    for (int k = 0; k < Kn; ++k) {
      int kk = kb + k;
      int m = (n * kk) & 511;
      float Fr = Tc[m] * SC512;
      float Fi = -Ts[m] * SC512;
      if (!imag_out) acc += Fr * wr[k] - Fi * wi[k];
      else           acc += Fr * wi[k] + Fi * wr[k];
    }
    Wt[(size_t)c * 512 + n] = (_Float16)acc;
  }
}

// ---------------- build irfft matrix, B-transposed, matching OXh layout ----------------
// iDt[n][k], n in [0,512), k in [0,544). k<264: e=k cos part; 264..527: e=k-264 sin part.

__global__ __launch_bounds__(256) void build_idt(_Float16* __restrict__ iDt) {
  int idx = blockIdx.x * 256 + threadIdx.x;
  const int total = 512 * 544;
  if (idx >= total) return;
  int n = idx / 544;
  int k = idx - n * 544;
  float val = 0.f;
  if (k < 264) {
    int e = k;
    if (e <= 256) {
      float ce = (e == 0 || e == 256) ? 1.f : 2.f;
      int m = (n * e) & 511;
      val = ce * SC512 * cosf((float)m * 0.0122718463030851f);
    }
  } else if (k < 528) {
    int e = k - 264;
    if (e <= 256) {
      float ce = (e == 0 || e == 256) ? 1.f : 2.f;
      int m = (n * e) & 511;
      val = -ce * SC512 * sinf((float)m * 0.0122718463030851f);
    }
  }
  iDt[(size_t)n * 544 + k] = (_Float16)val;
}

// ---------------- MFMA f16 GEMM: LHf = relu(x @ W + bias) * S_FOLD ----------------
// M=32768, N=1028 (17 tiles of 64), K=512. A fp32 converted in staging, B = Wt f16 [c][k].
// grid (17, 256), block 256 (4 waves); tile 128(M) x 64(N), BK=32.

__global__ __launch_bounds__(256) void gemm_main(
    const float* __restrict__ X, const _Float16* __restrict__ Wt,
    const float* __restrict__ lbr, const float* __restrict__ lbi,
    const float* __restrict__ hbr, const float* __restrict__ hbi,
    _Float16* __restrict__ LHf) {
  __shared__ __align__(16) char lds[33792];
  _Float16* As = (_Float16*)lds;              // [128][40]
  _Float16* Bs = (_Float16*)(lds + 10240);    // [64][40]
  float* CL = (float*)lds;                    // [128][66]

  int t = threadIdx.x;
  int w = t >> 6, L = t & 63, q = L >> 4, lc = L & 15;
  int row0 = blockIdx.y * 128;
  int n0 = blockIdx.x * 64;

  f32x4 acc[2][4];
#pragma unroll
  for (int i = 0; i < 2; ++i)
#pragma unroll
    for (int j = 0; j < 4; ++j) acc[i][j] = f32x4{0.f, 0.f, 0.f, 0.f};

  for (int k0 = 0; k0 < 512; k0 += 32) {
    // stage A (fp32 -> f16)
    {
      int m = t >> 1, half = t & 1;
      const float* src = X + (size_t)(row0 + m) * 512 + k0 + half * 16;
      float4 a0 = *(const float4*)(src + 0);
      float4 a1 = *(const float4*)(src + 4);
      float4 a2 = *(const float4*)(src + 8);
      float4 a3 = *(const float4*)(src + 12);
      f16x8 h0 = {(_Float16)a0.x, (_Float16)a0.y, (_Float16)a0.z, (_Float16)a0.w,
                  (_Float16)a1.x, (_Float16)a1.y, (_Float16)a1.z, (_Float16)a1.w};
      f16x8 h1 = {(_Float16)a2.x, (_Float16)a2.y, (_Float16)a2.z, (_Float16)a2.w,
                  (_Float16)a3.x, (_Float16)a3.y, (_Float16)a3.z, (_Float16)a3.w};
      *(f16x8*)(As + m * 40 + half * 16) = h0;
      *(f16x8*)(As + m * 40 + half * 16 + 8) = h1;
    }
    // stage B
    {
      int row = t >> 2, ch = t & 3;
      f16x8 bv = *(const f16x8*)(Wt + (size_t)(n0 + row) * 512 + k0 + ch * 8);
      *(f16x8*)(Bs + row * 40 + ch * 8) = bv;
    }
    __syncthreads();
#pragma unroll
    for (int sub = 0; sub < 2; ++sub) {
      f16x8 af = *(const f16x8*)(As + (w * 32 + sub * 16 + lc) * 40 + q * 8);
#pragma unroll
      for (int ns = 0; ns < 4; ++ns) {
        f16x8 bf = *(const f16x8*)(Bs + (ns * 16 + lc) * 40 + q * 8);
        acc[sub][ns] = __builtin_amdgcn_mfma_f32_16x16x32_f16(af, bf, acc[sub][ns], 0, 0, 0);
      }
    }
    __syncthreads();
  }

  // epilogue: reorder via LDS, then bias+relu+scale+f16 pack into LHf
#pragma unroll
  for (int sub = 0; sub < 2; ++sub)
#pragma unroll
    for (int ns = 0; ns < 4; ++ns)
#pragma unroll
      for (int r = 0; r < 4; ++r)
        CL[(w * 32 + sub * 16 + q * 4 + r) * 66 + ns * 16 + lc] = acc[sub][ns][r];
  __syncthreads();

#pragma unroll
  for (int rep = 0; rep < 8; ++rep) {
    int idx = rep * 256 + t;
    int row = idx >> 4;
    int c4 = idx & 15;
    f32x4 v = *(const f32x4*)(CL + row * 66 + c4 * 4);
    int rowg = row0 + row;
#pragma unroll
    for (int jj = 0; jj < 4; ++jj) {
      int c = n0 + c4 * 4 + jj;
      if (c < 1028) {
        int sub = (c >= 771) ? 3 : (c >= 514) ? 2 : (c >= 257) ? 1 : 0;
        int e = c - sub * 257;
        float bv = (sub == 0) ? lbr[e] : (sub == 1) ? lbi[e] : (sub == 2) ? hbr[e] : hbi[e];
        float val = fmaxf(v[jj] + bv, 0.f) * S_FOLD;
        LHf[(size_t)rowg * LD16 + sub * 264 + e] = (_Float16)val;
      }
    }
  }
}

// ---------------- repack K into MFMA B-frag-linear order ----------------
// Kpack chunk wc = (((b*2+pass)*2+comp)*32 + jt)*9 + ec ; chunk = [64 lanes][8 halves].
// Lane L: j = jt*16 + (L&15), e = ec*32 + (L>>4)*8 + i.

__global__ __launch_bounds__(256) void repack_K(
    const _Float16* __restrict__ LHf, _Float16* __restrict__ Kpack) {
  int t = threadIdx.x;
  int w = t >> 6, L = t & 63, q = L >> 4, lc = L & 15;
  int wc = blockIdx.x * 4 + w;
  int ec = wc % 9;
  int tmp = wc / 9;
  int jt = tmp & 31; tmp >>= 5;
  int comp = tmp & 1; tmp >>= 1;
  int pass = tmp & 1;
  int b = tmp >> 1;
  f16x8 v;
  if (ec == 8 && q > 0) {
    v = f16x8{(_Float16)0, (_Float16)0, (_Float16)0, (_Float16)0,
              (_Float16)0, (_Float16)0, (_Float16)0, (_Float16)0};
  } else {
    v = *(const f16x8*)(LHf + (size_t)(b * 512 + jt * 16 + lc) * LD16 +
                        pass * 528 + comp * 264 + ec * 32 + q * 8);
  }
  *(f16x8*)(Kpack + (size_t)wc * 512 + L * 8) = v;
}

// ---------------- repack V (low) into PV B-frag order via LDS transpose ----------------
// Vpack[b][comp][et(17)][ks(16)][64 lanes][8]; lane L: e = et*16+(L&15), j = ks*32+(L>>4)*8+i.

__global__ __launch_bounds__(256) void repack_V(
    const _Float16* __restrict__ LHf, _Float16* __restrict__ Vpack) {
  int bid = blockIdx.x;
  int et = bid % 17;
  int tmp = bid / 17;
  int comp = tmp & 1;
  int b = tmp >> 1;
  int t = threadIdx.x;
  __shared__ __align__(16) _Float16 tile[512 * 16];

  const f16x8 zero8 = {(_Float16)0, (_Float16)0, (_Float16)0, (_Float16)0,
                       (_Float16)0, (_Float16)0, (_Float16)0, (_Float16)0};
  for (int j = t; j < 512; j += 256) {
    const _Float16* src = LHf + (size_t)(b * 512 + j) * LD16 + comp * 264 + et * 16;
    f16x8 v0, v1;
    if (et < 16) {
      v0 = *(const f16x8*)(src);
      v1 = *(const f16x8*)(src + 8);
    } else {  // e = 256..271: only first 8 within sub-block (256 real, 257..263 zero)
      v0 = *(const f16x8*)(src);
      v1 = zero8;
    }
    *(f16x8*)(tile + j * 16) = v0;
    *(f16x8*)(tile + j * 16 + 8) = v1;
  }
  __syncthreads();

#pragma unroll
  for (int it = 0; it < 4; ++it) {
    int c2 = it * 256 + t;
    int ks = c2 >> 6;
    int L2 = c2 & 63;
    int q2 = L2 >> 4, lc2 = L2 & 15;
    f16x8 v;
#pragma unroll
    for (int i = 0; i < 8; ++i) v[i] = tile[(ks * 32 + q2 * 8 + i) * 16 + lc2];
    *(f16x8*)(Vpack + ((((size_t)(b * 2 + comp) * 17 + et) * 16 + ks) * 512) + L2 * 8) = v;
  }
}

// ---------------- DPP 16-lane reductions (VALU pipe, no DS latency) ----------------
// quad_perm [1,0,3,2] = 0xB1 (xor1), quad_perm [2,3,0,1] = 0x4E (xor2),
// row_half_mirror = 0x141 (combines quads within 8), row_mirror = 0x140 (combines 8s).

template <int CTRL>
__device__ __forceinline__ float dpp_f32(float x) {
  return __int_as_float(
      __builtin_amdgcn_update_dpp(0, __float_as_int(x), CTRL, 0xF, 0xF, true));
}

__device__ __forceinline__ float red_max16(float x) {
  x = fmaxf(x, dpp_f32<0xB1>(x));
  x = fmaxf(x, dpp_f32<0x4E>(x));
  x = fmaxf(x, dpp_f32<0x141>(x));
  x = fmaxf(x, dpp_f32<0x140>(x));
  return x;
}

__device__ __forceinline__ float red_sum16(float x) {
  x += dpp_f32<0xB1>(x);
  x += dpp_f32<0x4E>(x);
  x += dpp_f32<0x141>(x);
  x += dpp_f32<0x140>(x);
  return x;
}

// ---------------- MFMA f16 flash attention, single barrier per chunk ----------------
// Block = (b, 16 Q-rows), 4 waves; chunk = 64 j; wave owns jtile = jt*4+w.
// Per chunk: wave computes LOCAL softmax of its 16-j tile (DPP reduces, exp(v-mloc)),
// publishes P tile + (mloc,sumloc) to double-buffered LDS, ONE barrier, then every
// wave merges stats and rescales the P-fragments it loads by exp(mloc(owner)-mnew).
// Running max kept in two layouts: rows q*4+r (for acc rescale / l) and row lc (for
// P-frag scaling). No trailing barrier: sP/sM/sS double-buffered on chunk parity.

__global__ __launch_bounds__(256, 2) void attn_mfma3(
    const _Float16* __restrict__ LHf, const _Float16* __restrict__ Kpack,
    const _Float16* __restrict__ Vpack, _Float16* __restrict__ OXh) {
  int bid = blockIdx.x;
  int xcd = bid & 7;
  int ix = bid >> 3;
  int rt = ix & 31;
  int b = xcd + 8 * (ix >> 5);
  int t = threadIdx.x;
  int w = t >> 6, L = t & 63, q = L >> 4, lc = L & 15;

  __shared__ __align__(16) _Float16 sP[2][2][16][72];
  __shared__ __align__(16) float sM[2][2][16][4];
  __shared__ __align__(16) float sS[2][2][16][4];

  const f16x8 zero8 = {(_Float16)0, (_Float16)0, (_Float16)0, (_Float16)0,
                       (_Float16)0, (_Float16)0, (_Float16)0, (_Float16)0};

  // resident Q fragments (A-frag: m=lc, k=ec*32+q*8+i), gathered once
  const _Float16* qbase = LHf + (size_t)(b * 512 + rt * 16 + lc) * LD16;
  f16x8 Qf[2][9];
#pragma unroll
  for (int comp = 0; comp < 2; ++comp)
#pragma unroll
    for (int ec = 0; ec < 9; ++ec)
      Qf[comp][ec] = (ec == 8 && q != 0)
                         ? zero8
                         : *(const f16x8*)(qbase + comp * 264 + ec * 32 + q * 8);

  int t0 = (w == 0) ? 0 : (4 * w + 1);   // et tiles {0..4},{5..8},{9..12},{13..16}
  int nt = (w == 0) ? 5 : 4;

  f32x4 outR[5], outI[5];
#pragma unroll
  for (int i = 0; i < 5; ++i) {
    outR[i] = f32x4{0.f, 0.f, 0.f, 0.f};
    outI[i] = f32x4{0.f, 0.f, 0.f, 0.f};
  }

  for (int pass = 0; pass < 2; ++pass) {
    f32x4 accRR[5], accRI[5], accIR[5], accII[5];
    float m_r[4], l_r[4], m_i[4], l_i[4];
#pragma unroll
    for (int i = 0; i < 5; ++i) {
      accRR[i] = f32x4{0.f, 0.f, 0.f, 0.f};
      accRI[i] = f32x4{0.f, 0.f, 0.f, 0.f};
      accIR[i] = f32x4{0.f, 0.f, 0.f, 0.f};
      accII[i] = f32x4{0.f, 0.f, 0.f, 0.f};
    }
#pragma unroll
    for (int r = 0; r < 4; ++r) {
      m_r[r] = -3.0e38f; l_r[r] = 0.f;
      m_i[r] = -3.0e38f; l_i[r] = 0.f;
    }
    float mlcR = -3.0e38f, mlcI = -3.0e38f;  // running max for row lc (P-frag layout)

    for (int jt = 0; jt < 8; ++jt) {
      int buf = jt & 1;

      // ---- scores from Kpack (fully coalesced: base + L*16B) ----
      size_t kb0 = ((((size_t)(b * 2 + pass) * 2 + 0) * 32 + (jt * 4 + w)) * 9) * 512;
      size_t kb1 = ((((size_t)(b * 2 + pass) * 2 + 1) * 32 + (jt * 4 + w)) * 9) * 512;
      f32x4 sRR = f32x4{0.f, 0.f, 0.f, 0.f};
      f32x4 sII = f32x4{0.f, 0.f, 0.f, 0.f};
      f32x4 sRI = f32x4{0.f, 0.f, 0.f, 0.f};
      f32x4 sIR = f32x4{0.f, 0.f, 0.f, 0.f};
#pragma unroll
      for (int ec = 0; ec < 9; ++ec) {
        f16x8 bKr = *(const f16x8*)(Kpack + kb0 + (size_t)ec * 512 + L * 8);
        f16x8 bKi = *(const f16x8*)(Kpack + kb1 + (size_t)ec * 512 + L * 8);
        sRR = __builtin_amdgcn_mfma_f32_16x16x32_f16(Qf[0][ec], bKr, sRR, 0, 0, 0);
        sII = __builtin_amdgcn_mfma_f32_16x16x32_f16(Qf[1][ec], bKi, sII, 0, 0, 0);
        sRI = __builtin_amdgcn_mfma_f32_16x16x32_f16(Qf[0][ec], bKi, sRI, 0, 0, 0);
        sIR = __builtin_amdgcn_mfma_f32_16x16x32_f16(Qf[1][ec], bKr, sIR, 0, 0, 0);
      }

      // ---- phase A: local softmax of this wave's 16-j tile, publish ----
#pragma unroll
      for (int r = 0; r < 4; ++r) {
        float vr = sRR[r] - sII[r];
        float vi = sRI[r] + sIR[r];
        float mlr = red_max16(vr);
        float mli = red_max16(vi);
        float ur = __expf(vr - mlr);
        float ui = __expf(vi - mli);
        int row = q * 4 + r;
        sP[buf][0][row][w * 16 + lc] = (_Float16)ur;
        sP[buf][1][row][w * 16 + lc] = (_Float16)ui;
        float sr = red_sum16(ur);
        float si = red_sum16(ui);
        if (lc == 0) {
          sM[buf][0][row][w] = mlr;
          sS[buf][0][row][w] = sr;
          sM[buf][1][row][w] = mli;
          sS[buf][1][row][w] = si;
        }
      }
      __syncthreads();  // the ONLY barrier per chunk

      // ---- phase B: merge stats for own (q,r) rows ----
      float fac_r[4], fac_i[4];
#pragma unroll
      for (int r = 0; r < 4; ++r) {
        int row = q * 4 + r;
        {
          f32x4 g = *(const f32x4*)&sM[buf][0][row][0];
          float mt = fmaxf(fmaxf(g[0], g[1]), fmaxf(g[2], g[3]));
          float mn = fmaxf(m_r[r], mt);
          fac_r[r] = __expf(m_r[r] - mn);
          m_r[r] = mn;
          f32x4 s4 = *(const f32x4*)&sS[buf][0][row][0];
          l_r[r] = l_r[r] * fac_r[r] + s4[0] * __expf(g[0] - mn) +
                   s4[1] * __expf(g[1] - mn) + s4[2] * __expf(g[2] - mn) +
                   s4[3] * __expf(g[3] - mn);
        }
        {
          f32x4 g = *(const f32x4*)&sM[buf][1][row][0];
          float mt = fmaxf(fmaxf(g[0], g[1]), fmaxf(g[2], g[3]));
          float mn = fmaxf(m_i[r], mt);
          fac_i[r] = __expf(m_i[r] - mn);
          m_i[r] = mn;
          f32x4 s4 = *(const f32x4*)&sS[buf][1][row][0];
          l_i[r] = l_i[r] * fac_i[r] + s4[0] * __expf(g[0] - mn) +
                   s4[1] * __expf(g[1] - mn) + s4[2] * __expf(g[2] - mn) +
                   s4[3] * __expf(g[3] - mn);
        }
      }

      // ---- per-row(lc) rescale factors for P frags (named scalars: no scratch) ----
      float sclR0, sclR1, sclR2, sclR3, sclI0, sclI1, sclI2, sclI3;
      {
        f32x4 g = *(const f32x4*)&sM[buf][0][lc][0];
        float mt = fmaxf(fmaxf(g[0], g[1]), fmaxf(g[2], g[3]));
        float mn = fmaxf(mlcR, mt);
        mlcR = mn;
        sclR0 = __expf(g[0] - mn);
        sclR1 = __expf(g[1] - mn);
        sclR2 = __expf(g[2] - mn);
        sclR3 = __expf(g[3] - mn);
      }
      {
        f32x4 g = *(const f32x4*)&sM[buf][1][lc][0];
        float mt = fmaxf(fmaxf(g[0], g[1]), fmaxf(g[2], g[3]));
        float mn = fmaxf(mlcI, mt);
        mlcI = mn;
        sclI0 = __expf(g[0] - mn);
        sclI1 = __expf(g[1] - mn);
        sclI2 = __expf(g[2] - mn);
        sclI3 = __expf(g[3] - mn);
      }
      int h = q >> 1;  // frag at ks spans j-tile ks*2+h -> owner wave ks*2+h
      _Float16 fr0 = (_Float16)(h ? sclR1 : sclR0);
      _Float16 fr1 = (_Float16)(h ? sclR3 : sclR2);
      _Float16 fi0 = (_Float16)(h ? sclI1 : sclI0);
      _Float16 fi1 = (_Float16)(h ? sclI3 : sclI2);

      // ---- PV: A-frags from sP (rescaled), B-frags coalesced from Vpack ----
      f16x8 aPr[2], aPi[2];
      aPr[0] = *(const f16x8*)&sP[buf][0][lc][q * 8];
      aPi[0] = *(const f16x8*)&sP[buf][1][lc][q * 8];
      aPr[1] = *(const f16x8*)&sP[buf][0][lc][32 + q * 8];
      aPi[1] = *(const f16x8*)&sP[buf][1][lc][32 + q * 8];
#pragma unroll
      for (int i = 0; i < 8; ++i) {
        aPr[0][i] *= fr0; aPi[0][i] *= fi0;
        aPr[1][i] *= fr1; aPi[1][i] *= fi1;
      }

#pragma unroll
      for (int ti = 0; ti < 5; ++ti) {
        if (ti < nt) {
          int et = t0 + ti;
#pragma unroll
          for (int r = 0; r < 4; ++r) {
            accRR[ti][r] *= fac_r[r]; accRI[ti][r] *= fac_r[r];
            accIR[ti][r] *= fac_i[r]; accII[ti][r] *= fac_i[r];
          }
#pragma unroll
          for (int ks = 0; ks < 2; ++ks) {
            size_t vb = (((size_t)(b * 2 + 0) * 17 + et) * 16 + (jt * 2 + ks)) * 512;
            size_t vb2 = (((size_t)(b * 2 + 1) * 17 + et) * 16 + (jt * 2 + ks)) * 512;
            f16x8 bVr = *(const f16x8*)(Vpack + vb + L * 8);
            f16x8 bVi = *(const f16x8*)(Vpack + vb2 + L * 8);
            accRR[ti] = __builtin_amdgcn_mfma_f32_16x16x32_f16(aPr[ks], bVr, accRR[ti], 0, 0, 0);
            accRI[ti] = __builtin_amdgcn_mfma_f32_16x16x32_f16(aPr[ks], bVi, accRI[ti], 0, 0, 0);
            accIR[ti] = __builtin_amdgcn_mfma_f32_16x16x32_f16(aPi[ks], bVr, accIR[ti], 0, 0, 0);
            accII[ti] = __builtin_amdgcn_mfma_f32_16x16x32_f16(aPi[ks], bVi, accII[ti], 0, 0, 0);
          }
        }
      }
      // no trailing barrier: next chunk writes the other sP/sM/sS buffer
    }

    // ---- finalize pass (INV_S compensates V pre-scaling) ----
#pragma unroll
    for (int r = 0; r < 4; ++r) {
      float ir = INV_S / l_r[r];
      float ii = INV_S / l_i[r];
#pragma unroll
      for (int ti = 0; ti < 5; ++ti) {
        if (ti < nt) {
          outR[ti][r] += accRR[ti][r] * ir - accII[ti][r] * ii;
          outI[ti][r] += accRI[ti][r] * ir + accIR[ti][r] * ii;
        }
      }
    }
  }

  // ---- store OXh f16 rows into LHf[.][528..1056) ----
  _Float16* obase = OXh + (size_t)(b * 512 + rt * 16) * LD16 + OXOFF;
#pragma unroll
  for (int ti = 0; ti < 5; ++ti) {
    if (ti < nt) {
      int e = (t0 + ti) * 16 + lc;
      if (e < 257) {
#pragma unroll
        for (int r = 0; r < 4; ++r) {
          _Float16* dst = obase + (size_t)(q * 4 + r) * LD16;
          dst[e] = (_Float16)outR[ti][r];
          dst[264 + e] = (_Float16)outI[ti][r];
        }
      }
    }
  }
}

// ---------------- MFMA f16 GEMM: out = OXh @ iDt ----------------
// M=32768, N=512 (8 tiles), K=528 (pad 544). A = LHf+OXOFF (f16, ld 1056).

__global__ __launch_bounds__(256) void gemm_irfft(
    const _Float16* __restrict__ LHf, const _Float16* __restrict__ iDt,
    float* __restrict__ out) {
  __shared__ __align__(16) char lds[33792];
  _Float16* As = (_Float16*)lds;              // [128][40]
  _Float16* Bs = (_Float16*)(lds + 10240);    // [64][40]
  float* CL = (float*)lds;                    // [128][66]

  int t = threadIdx.x;
  int w = t >> 6, L = t & 63, q = L >> 4, lc = L & 15;
  int row0 = blockIdx.y * 128;
  int n0 = blockIdx.x * 64;

  const f16x8 zero8 = {(_Float16)0, (_Float16)0, (_Float16)0, (_Float16)0,
                       (_Float16)0, (_Float16)0, (_Float16)0, (_Float16)0};

  f32x4 acc[2][4];
#pragma unroll
  for (int i = 0; i < 2; ++i)
#pragma unroll
    for (int j = 0; j < 4; ++j) acc[i][j] = f32x4{0.f, 0.f, 0.f, 0.f};

  for (int k0 = 0; k0 < 544; k0 += 32) {
    {
      int m = t >> 1, half = t & 1;
      int kk = k0 + half * 16;
      f16x8 h0, h1;
      if (kk < 528) {
        const _Float16* src = LHf + (size_t)(row0 + m) * LD16 + OXOFF + kk;
        h0 = *(const f16x8*)(src);
        h1 = *(const f16x8*)(src + 8);
      } else {
        h0 = zero8; h1 = zero8;
      }
      *(f16x8*)(As + m * 40 + half * 16) = h0;
      *(f16x8*)(As + m * 40 + half * 16 + 8) = h1;
    }
    {
      int row = t >> 2, ch = t & 3;
      f16x8 bv = *(const f16x8*)(iDt + (size_t)(n0 + row) * 544 + k0 + ch * 8);
      *(f16x8*)(Bs + row * 40 + ch * 8) = bv;
    }
    __syncthreads();
#pragma unroll
    for (int sub = 0; sub < 2; ++sub) {
      f16x8 af = *(const f16x8*)(As + (w * 32 + sub * 16 + lc) * 40 + q * 8);
#pragma unroll
      for (int ns = 0; ns < 4; ++ns) {
        f16x8 bf = *(const f16x8*)(Bs + (ns * 16 + lc) * 40 + q * 8);
        acc[sub][ns] = __builtin_amdgcn_mfma_f32_16x16x32_f16(af, bf, acc[sub][ns], 0, 0, 0);
      }
    }
    __syncthreads();
  }

#pragma unroll
  for (int sub = 0; sub < 2; ++sub)
#pragma unroll
    for (int ns = 0; ns < 4; ++ns)
#pragma unroll
      for (int r = 0; r < 4; ++r)
        CL[(w * 32 + sub * 16 + q * 4 + r) * 66 + ns * 16 + lc] = acc[sub][ns][r];
  __syncthreads();

#pragma unroll
  for (int rep = 0; rep < 8; ++rep) {
    int idx = rep * 256 + t;
    int row = idx >> 4;
    int c4 = idx & 15;
    f32x4 v = *(const f32x4*)(CL + row * 66 + c4 * 4);
    float4 o = {v[0], v[1], v[2], v[3]};
    *(float4*)(out + (size_t)(row0 + row) * 512 + n0 + c4 * 4) = o;
  }
}

// ---------------- launch ----------------

extern "C" void kernel_launch(void* const* d_in, const int* in_sizes, int n_in,
                              void* d_out, int out_size, void* d_ws, size_t ws_size,
                              hipStream_t stream) {
  const float* x   = (const float*)d_in[0];
  const float* l1r = (const float*)d_in[1];
  const float* l1i = (const float*)d_in[2];
  const float* h1r = (const float*)d_in[3];
  const float* h1i = (const float*)d_in[4];
  const float* lbr = (const float*)d_in[5];
  const float* lbi = (const float*)d_in[6];
  const float* hbr = (const float*)d_in[7];
  const float* hbi = (const float*)d_in[8];
  float* out = (float*)d_out;

  _Float16* ws = (_Float16*)d_ws;
  size_t off = 0;
  _Float16* LHf = ws + off;   off += (size_t)32768 * LD16;        // 69.2 MB
  _Float16* Kpack = ws + off; off += (size_t)73728 * 512;         // 75.5 MB
  _Float16* Vpack = ws + off; off += (size_t)64 * 2 * 17 * 16 * 512;  // 35.7 MB
  _Float16* Wt = ws + off;    off += (size_t)1088 * 512;          // 1.1 MB
  _Float16* iDt = ws + off;   off += (size_t)512 * 544;           // 0.6 MB

  hipMemsetAsync(LHf, 0, (size_t)32768 * LD16 * 2, stream);

  build_W<<<1088, 256, 0, stream>>>(l1r, l1i, h1r, h1i, Wt);
  build_idt<<<(512 * 544 + 255) / 256, 256, 0, stream>>>(iDt);

  gemm_main<<<dim3(17, 256), 256, 0, stream>>>(x, Wt, lbr, lbi, hbr, hbi, LHf);
  repack_K<<<73728 / 4, 256, 0, stream>>>(LHf, Kpack);
  repack_V<<<64 * 2 * 17, 256, 0, stream>>>(LHf, Vpack);
  attn_mfma3<<<2048, 256, 0, stream>>>(LHf, Kpack, Vpack, LHf);
  gemm_irfft<<<dim3(8, 256), 256, 0, stream>>>(LHf, iDt, out);
}

// Round 2
// 864.615 us; speedup vs baseline: 1.3378x; 1.3032x over previous
//
#include <hip/hip_runtime.h>
#include <math.h>

// B=64, C=512, S=512, E=257, LK=128, HK=129.
// high_x is dead code in the reference: only low_x = attn(low,low,low)+attn(low,high,low).
//
// Pipeline (all heavy math on MFMA f16):
//  1. build_W: Wt[c][n] f16 = combined rfft+projection weight (512 -> 1028), B-transposed
//  2. build_idt: iDt[n][k] f16 = irfft matrix matching OXh row layout [re264|im264]
//  3. gemm_main (MFMA f16): LHf = relu(x @ W + bias) * S_FOLD, f16 rows [lr|li|hr|hi] (264 pad)
//  4. repack_K: LHf -> Kpack in exact MFMA B-frag order (coalesced attention loads)
//  5. repack_V: LHf low -> Vpack (LDS transpose) in PV B-frag order
//  6. attn (MFMA f16 flash): single-barrier-per-chunk, DPP softmax, Q in LDS (reg headroom)
//  7. gemm_irfft (MFMA f16): out = OXh @ iDt
//
// ws: LHf 69.2 MB + Kpack 75.5 MB + Vpack 35.7 MB + Wt 1.1 MB + iDt 0.6 MB ~= 182 MB.

#define LD16 1056   // halves per LHf row: [lr 264 | li 264 | hr 264 | hi 264]
#define OXOFF 528   // OXh f16 output written into LHf[row][528..1056): [re 264 | im 264]

typedef __attribute__((ext_vector_type(4))) _Float16 f16x4;
typedef __attribute__((ext_vector_type(8))) _Float16 f16x8;
typedef __attribute__((ext_vector_type(4))) float f32x4;

#define S_FOLD 0.24975653f    // sqrt(1/sqrt(257))
#define INV_S  4.0039005f     // 1/S_FOLD
#define SC512  0.0441941738241592f   // 1/sqrt(512)

// ---------------- build combined rfft+projection weight, B-transposed ----------------
// Wt[c][n], c in [0,1088), n in [0,512). c>=1028 -> 0.
// c<257: low_r; 257..513: low_i; 514..770: high_r; 771..1027: high_i.

__global__ __launch_bounds__(256) void build_W(
    const float* __restrict__ l1r, const float* __restrict__ l1i,
    const float* __restrict__ h1r, const float* __restrict__ h1i,
    _Float16* __restrict__ Wt) {
  int c = blockIdx.x;
  int t = threadIdx.x;
  if (c >= 1028) {
    for (int n = t; n < 512; n += 256) Wt[(size_t)c * 512 + n] = (_Float16)0.0f;
    return;
  }
  __shared__ float Tc[512], Ts[512];
  __shared__ float wr[132], wi[132];
  for (int i = t; i < 512; i += 256) {
    float ang = (float)i * 0.0122718463030851f;  // 2*pi/512
    Tc[i] = cosf(ang);
    Ts[i] = sinf(ang);
  }
  int sub = (c >= 771) ? 3 : (c >= 514) ? 2 : (c >= 257) ? 1 : 0;
  int e = c - sub * 257;
  int Kn = (sub < 2) ? 128 : 129;
  int kb = (sub < 2) ? 0 : 128;
  if (t < Kn) {
    if (sub < 2) { wr[t] = l1r[t * 257 + e]; wi[t] = l1i[t * 257 + e]; }
    else         { wr[t] = h1r[t * 257 + e]; wi[t] = h1i[t * 257 + e]; }
  }
  __syncthreads();
  bool imag_out = (sub & 1);
  for (int n = t; n < 512; n += 256) {
    float acc = 0.f;
    for (int k = 0; k < Kn; ++k) {
      int kk = kb + k;
      int m = (n * kk) & 511;
      float Fr = Tc[m] * SC512;
      float Fi = -Ts[m] * SC512;
      if (!imag_out) acc += Fr * wr[k] - Fi * wi[k];
      else           acc += Fr * wi[k] + Fi * wr[k];
    }
    Wt[(size_t)c * 512 + n] = (_Float16)acc;
  }
}

// ---------------- build irfft matrix, B-transposed, matching OXh layout ----------------
// iDt[n][k], n in [0,512), k in [0,544). k<264: e=k cos part; 264..527: e=k-264 sin part.

__global__ __launch_bounds__(256) void build_idt(_Float16* __restrict__ iDt) {
  int idx = blockIdx.x * 256 + threadIdx.x;
  const int total = 512 * 544;
  if (idx >= total) return;
  int n = idx / 544;
  int k = idx - n * 544;
  float val = 0.f;
  if (k < 264) {
    int e = k;
    if (e <= 256) {
      float ce = (e == 0 || e == 256) ? 1.f : 2.f;
      int m = (n * e) & 511;
      val = ce * SC512 * cosf((float)m * 0.0122718463030851f);
    }
  } else if (k < 528) {
    int e = k - 264;
    if (e <= 256) {
      float ce = (e == 0 || e == 256) ? 1.f : 2.f;
      int m = (n * e) & 511;
      val = -ce * SC512 * sinf((float)m * 0.0122718463030851f);
    }
  }
  iDt[(size_t)n * 544 + k] = (_Float16)val;
}

// ---------------- MFMA f16 GEMM: LHf = relu(x @ W + bias) * S_FOLD ----------------
// M=32768, N=1028 (17 tiles of 64), K=512. A fp32 converted in staging, B = Wt f16 [c][k].
// grid (17, 256), block 256 (4 waves); tile 128(M) x 64(N), BK=32.

__global__ __launch_bounds__(256) void gemm_main(
    const float* __restrict__ X, const _Float16* __restrict__ Wt,
    const float* __restrict__ lbr, const float* __restrict__ lbi,
    const float* __restrict__ hbr, const float* __restrict__ hbi,
    _Float16* __restrict__ LHf) {
  __shared__ __align__(16) char lds[33792];
  _Float16* As = (_Float16*)lds;              // [128][40]
  _Float16* Bs = (_Float16*)(lds + 10240);    // [64][40]
  float* CL = (float*)lds;                    // [128][66]

  int t = threadIdx.x;
  int w = t >> 6, L = t & 63, q = L >> 4, lc = L & 15;
  int row0 = blockIdx.y * 128;
  int n0 = blockIdx.x * 64;

  f32x4 acc[2][4];
#pragma unroll
  for (int i = 0; i < 2; ++i)
#pragma unroll
    for (int j = 0; j < 4; ++j) acc[i][j] = f32x4{0.f, 0.f, 0.f, 0.f};

  for (int k0 = 0; k0 < 512; k0 += 32) {
    // stage A (fp32 -> f16)
    {
      int m = t >> 1, half = t & 1;
      const float* src = X + (size_t)(row0 + m) * 512 + k0 + half * 16;
      float4 a0 = *(const float4*)(src + 0);
      float4 a1 = *(const float4*)(src + 4);
      float4 a2 = *(const float4*)(src + 8);
      float4 a3 = *(const float4*)(src + 12);
      f16x8 h0 = {(_Float16)a0.x, (_Float16)a0.y, (_Float16)a0.z, (_Float16)a0.w,
                  (_Float16)a1.x, (_Float16)a1.y, (_Float16)a1.z, (_Float16)a1.w};
      f16x8 h1 = {(_Float16)a2.x, (_Float16)a2.y, (_Float16)a2.z, (_Float16)a2.w,
                  (_Float16)a3.x, (_Float16)a3.y, (_Float16)a3.z, (_Float16)a3.w};
      *(f16x8*)(As + m * 40 + half * 16) = h0;
      *(f16x8*)(As + m * 40 + half * 16 + 8) = h1;
    }
    // stage B
    {
      int row = t >> 2, ch = t & 3;
      f16x8 bv = *(const f16x8*)(Wt + (size_t)(n0 + row) * 512 + k0 + ch * 8);
      *(f16x8*)(Bs + row * 40 + ch * 8) = bv;
    }
    __syncthreads();
#pragma unroll
    for (int sub = 0; sub < 2; ++sub) {
      f16x8 af = *(const f16x8*)(As + (w * 32 + sub * 16 + lc) * 40 + q * 8);
#pragma unroll
      for (int ns = 0; ns < 4; ++ns) {
        f16x8 bf = *(const f16x8*)(Bs + (ns * 16 + lc) * 40 + q * 8);
        acc[sub][ns] = __builtin_amdgcn_mfma_f32_16x16x32_f16(af, bf, acc[sub][ns], 0, 0, 0);
      }
    }
    __syncthreads();
  }

  // epilogue: reorder via LDS, then bias+relu+scale+f16 pack into LHf
#pragma unroll
  for (int sub = 0; sub < 2; ++sub)
#pragma unroll
    for (int ns = 0; ns < 4; ++ns)
#pragma unroll
      for (int r = 0; r < 4; ++r)
        CL[(w * 32 + sub * 16 + q * 4 + r) * 66 + ns * 16 + lc] = acc[sub][ns][r];
  __syncthreads();

#pragma unroll
  for (int rep = 0; rep < 8; ++rep) {
    int idx = rep * 256 + t;
    int row = idx >> 4;
    int c4 = idx & 15;
    f32x4 v = *(const f32x4*)(CL + row * 66 + c4 * 4);
    int rowg = row0 + row;
#pragma unroll
    for (int jj = 0; jj < 4; ++jj) {
      int c = n0 + c4 * 4 + jj;
      if (c < 1028) {
        int sub = (c >= 771) ? 3 : (c >= 514) ? 2 : (c >= 257) ? 1 : 0;
        int e = c - sub * 257;
        float bv = (sub == 0) ? lbr[e] : (sub == 1) ? lbi[e] : (sub == 2) ? hbr[e] : hbi[e];
        float val = fmaxf(v[jj] + bv, 0.f) * S_FOLD;
        LHf[(size_t)rowg * LD16 + sub * 264 + e] = (_Float16)val;
      }
    }
  }
}

// ---------------- repack K into MFMA B-frag-linear order ----------------
// Kpack chunk wc = (((b*2+pass)*2+comp)*32 + jt)*9 + ec ; chunk = [64 lanes][8 halves].
// Lane L: j = jt*16 + (L&15), e = ec*32 + (L>>4)*8 + i.

__global__ __launch_bounds__(256) void repack_K(
    const _Float16* __restrict__ LHf, _Float16* __restrict__ Kpack) {
  int t = threadIdx.x;
  int w = t >> 6, L = t & 63, q = L >> 4, lc = L & 15;
  int wc = blockIdx.x * 4 + w;
  int ec = wc % 9;
  int tmp = wc / 9;
  int jt = tmp & 31; tmp >>= 5;
  int comp = tmp & 1; tmp >>= 1;
  int pass = tmp & 1;
  int b = tmp >> 1;
  f16x8 v;
  if (ec == 8 && q > 0) {
    v = f16x8{(_Float16)0, (_Float16)0, (_Float16)0, (_Float16)0,
              (_Float16)0, (_Float16)0, (_Float16)0, (_Float16)0};
  } else {
    v = *(const f16x8*)(LHf + (size_t)(b * 512 + jt * 16 + lc) * LD16 +
                        pass * 528 + comp * 264 + ec * 32 + q * 8);
  }
  *(f16x8*)(Kpack + (size_t)wc * 512 + L * 8) = v;
}

// ---------------- repack V (low) into PV B-frag order via LDS transpose ----------------
// Vpack[b][comp][et(17)][ks(16)][64 lanes][8]; lane L: e = et*16+(L&15), j = ks*32+(L>>4)*8+i.

__global__ __launch_bounds__(256) void repack_V(
    const _Float16* __restrict__ LHf, _Float16* __restrict__ Vpack) {
  int bid = blockIdx.x;
  int et = bid % 17;
  int tmp = bid / 17;
  int comp = tmp & 1;
  int b = tmp >> 1;
  int t = threadIdx.x;
  __shared__ __align__(16) _Float16 tile[512 * 16];

  const f16x8 zero8 = {(_Float16)0, (_Float16)0, (_Float16)0, (_Float16)0,
                       (_Float16)0, (_Float16)0, (_Float16)0, (_Float16)0};
  for (int j = t; j < 512; j += 256) {
    const _Float16* src = LHf + (size_t)(b * 512 + j) * LD16 + comp * 264 + et * 16;
    f16x8 v0, v1;
    if (et < 16) {
      v0 = *(const f16x8*)(src);
      v1 = *(const f16x8*)(src + 8);
    } else {  // e = 256..271: only first 8 within sub-block (256 real, 257..263 zero)
      v0 = *(const f16x8*)(src);
      v1 = zero8;
    }
    *(f16x8*)(tile + j * 16) = v0;
    *(f16x8*)(tile + j * 16 + 8) = v1;
  }
  __syncthreads();

#pragma unroll
  for (int it = 0; it < 4; ++it) {
    int c2 = it * 256 + t;
    int ks = c2 >> 6;
    int L2 = c2 & 63;
    int q2 = L2 >> 4, lc2 = L2 & 15;
    f16x8 v;
#pragma unroll
    for (int i = 0; i < 8; ++i) v[i] = tile[(ks * 32 + q2 * 8 + i) * 16 + lc2];
    *(f16x8*)(Vpack + ((((size_t)(b * 2 + comp) * 17 + et) * 16 + ks) * 512) + L2 * 8) = v;
  }
}

// ---------------- DPP 16-lane reductions (VALU pipe, no DS latency) ----------------

template <int CTRL>
__device__ __forceinline__ float dpp_f32(float x) {
  return __int_as_float(
      __builtin_amdgcn_update_dpp(0, __float_as_int(x), CTRL, 0xF, 0xF, true));
}

__device__ __forceinline__ float red_max16(float x) {
  x = fmaxf(x, dpp_f32<0xB1>(x));
  x = fmaxf(x, dpp_f32<0x4E>(x));
  x = fmaxf(x, dpp_f32<0x141>(x));
  x = fmaxf(x, dpp_f32<0x140>(x));
  return x;
}

__device__ __forceinline__ float red_sum16(float x) {
  x += dpp_f32<0xB1>(x);
  x += dpp_f32<0x4E>(x);
  x += dpp_f32<0x141>(x);
  x += dpp_f32<0x140>(x);
  return x;
}

// ---------------- MFMA f16 flash attention ----------------
// Single barrier per chunk, DPP local softmax, double-buffered sP/sM/sS.
// Q fragments live in LDS (sQ) instead of 72 resident VGPRs: the freed registers
// let the scheduler keep many 16B Kpack/Vpack loads in flight (the round-1 profile
// showed ~24.5k cy/chunk ~= 56 loads fully serialized at ~360cy; reg pressure at the
// 256-cap prevented load pipelining).

__global__ __launch_bounds__(256, 2) void attn_mfma3(
    const _Float16* __restrict__ LHf, const _Float16* __restrict__ Kpack,
    const _Float16* __restrict__ Vpack, _Float16* __restrict__ OXh) {
  int bid = blockIdx.x;
  int xcd = bid & 7;
  int ix = bid >> 3;
  int rt = ix & 31;
  int b = xcd + 8 * (ix >> 5);
  int t = threadIdx.x;
  int w = t >> 6, L = t & 63, q = L >> 4, lc = L & 15;

  __shared__ __align__(16) _Float16 sQ[2][16][296];  // stride 296 halves: 2-way banks only
  __shared__ __align__(16) _Float16 sP[2][2][16][72];
  __shared__ __align__(16) float sM[2][2][16][4];
  __shared__ __align__(16) float sS[2][2][16][4];

  const f16x8 zero8 = {(_Float16)0, (_Float16)0, (_Float16)0, (_Float16)0,
                       (_Float16)0, (_Float16)0, (_Float16)0, (_Float16)0};

  // fill sQ (A-frag layout: row=lc, k=ec*32+q*8+i), 18 frag-groups over 4 waves
  {
    const _Float16* qbase = LHf + (size_t)(b * 512 + rt * 16 + lc) * LD16;
    for (int g = w; g < 18; g += 4) {
      int comp = g / 9, ec = g - (comp * 9);
      f16x8 v = (ec == 8 && q != 0)
                    ? zero8
                    : *(const f16x8*)(qbase + comp * 264 + ec * 32 + q * 8);
      *(f16x8*)(&sQ[comp][lc][ec * 32 + q * 8]) = v;
    }
  }
  __syncthreads();

  int t0 = (w == 0) ? 0 : (4 * w + 1);   // et tiles {0..4},{5..8},{9..12},{13..16}
  int nt = (w == 0) ? 5 : 4;

  f32x4 outR[5], outI[5];
#pragma unroll
  for (int i = 0; i < 5; ++i) {
    outR[i] = f32x4{0.f, 0.f, 0.f, 0.f};
    outI[i] = f32x4{0.f, 0.f, 0.f, 0.f};
  }

  for (int pass = 0; pass < 2; ++pass) {
    f32x4 accRR[5], accRI[5], accIR[5], accII[5];
    float m_r[4], l_r[4], m_i[4], l_i[4];
#pragma unroll
    for (int i = 0; i < 5; ++i) {
      accRR[i] = f32x4{0.f, 0.f, 0.f, 0.f};
      accRI[i] = f32x4{0.f, 0.f, 0.f, 0.f};
      accIR[i] = f32x4{0.f, 0.f, 0.f, 0.f};
      accII[i] = f32x4{0.f, 0.f, 0.f, 0.f};
    }
#pragma unroll
    for (int r = 0; r < 4; ++r) {
      m_r[r] = -3.0e38f; l_r[r] = 0.f;
      m_i[r] = -3.0e38f; l_i[r] = 0.f;
    }
    float mlcR = -3.0e38f, mlcI = -3.0e38f;  // running max for row lc (P-frag layout)

    for (int jt = 0; jt < 8; ++jt) {
      int buf = jt & 1;

      // ---- scores: K B-frags coalesced from Kpack, Q A-frags from sQ ----
      size_t kb0 = ((((size_t)(b * 2 + pass) * 2 + 0) * 32 + (jt * 4 + w)) * 9) * 512;
      size_t kb1 = ((((size_t)(b * 2 + pass) * 2 + 1) * 32 + (jt * 4 + w)) * 9) * 512;
      f32x4 sRR = f32x4{0.f, 0.f, 0.f, 0.f};
      f32x4 sII = f32x4{0.f, 0.f, 0.f, 0.f};
      f32x4 sRI = f32x4{0.f, 0.f, 0.f, 0.f};
      f32x4 sIR = f32x4{0.f, 0.f, 0.f, 0.f};
      __builtin_amdgcn_s_setprio(1);
#pragma unroll
      for (int ec = 0; ec < 9; ++ec) {
        f16x8 bKr = *(const f16x8*)(Kpack + kb0 + (size_t)ec * 512 + L * 8);
        f16x8 bKi = *(const f16x8*)(Kpack + kb1 + (size_t)ec * 512 + L * 8);
        f16x8 q0 = *(const f16x8*)(&sQ[0][lc][ec * 32 + q * 8]);
        f16x8 q1 = *(const f16x8*)(&sQ[1][lc][ec * 32 + q * 8]);
        sRR = __builtin_amdgcn_mfma_f32_16x16x32_f16(q0, bKr, sRR, 0, 0, 0);
        sII = __builtin_amdgcn_mfma_f32_16x16x32_f16(q1, bKi, sII, 0, 0, 0);
        sRI = __builtin_amdgcn_mfma_f32_16x16x32_f16(q0, bKi, sRI, 0, 0, 0);
        sIR = __builtin_amdgcn_mfma_f32_16x16x32_f16(q1, bKr, sIR, 0, 0, 0);
      }
      __builtin_amdgcn_s_setprio(0);

      // ---- phase A: local softmax of this wave's 16-j tile, publish ----
#pragma unroll
      for (int r = 0; r < 4; ++r) {
        float vr = sRR[r] - sII[r];
        float vi = sRI[r] + sIR[r];
        float mlr = red_max16(vr);
        float mli = red_max16(vi);
        float ur = __expf(vr - mlr);
        float ui = __expf(vi - mli);
        int row = q * 4 + r;
        sP[buf][0][row][w * 16 + lc] = (_Float16)ur;
        sP[buf][1][row][w * 16 + lc] = (_Float16)ui;
        float sr = red_sum16(ur);
        float si = red_sum16(ui);
        if (lc == 0) {
          sM[buf][0][row][w] = mlr;
          sS[buf][0][row][w] = sr;
          sM[buf][1][row][w] = mli;
          sS[buf][1][row][w] = si;
        }
      }
      __syncthreads();  // the ONLY barrier per chunk

      // ---- phase B: merge stats for own (q,r) rows ----
      float fac_r[4], fac_i[4];
#pragma unroll
      for (int r = 0; r < 4; ++r) {
        int row = q * 4 + r;
        {
          f32x4 g = *(const f32x4*)&sM[buf][0][row][0];
          float mt = fmaxf(fmaxf(g[0], g[1]), fmaxf(g[2], g[3]));
          float mn = fmaxf(m_r[r], mt);
          fac_r[r] = __expf(m_r[r] - mn);
          m_r[r] = mn;
          f32x4 s4 = *(const f32x4*)&sS[buf][0][row][0];
          l_r[r] = l_r[r] * fac_r[r] + s4[0] * __expf(g[0] - mn) +
                   s4[1] * __expf(g[1] - mn) + s4[2] * __expf(g[2] - mn) +
                   s4[3] * __expf(g[3] - mn);
        }
        {
          f32x4 g = *(const f32x4*)&sM[buf][1][row][0];
          float mt = fmaxf(fmaxf(g[0], g[1]), fmaxf(g[2], g[3]));
          float mn = fmaxf(m_i[r], mt);
          fac_i[r] = __expf(m_i[r] - mn);
          m_i[r] = mn;
          f32x4 s4 = *(const f32x4*)&sS[buf][1][row][0];
          l_i[r] = l_i[r] * fac_i[r] + s4[0] * __expf(g[0] - mn) +
                   s4[1] * __expf(g[1] - mn) + s4[2] * __expf(g[2] - mn) +
                   s4[3] * __expf(g[3] - mn);
        }
      }

      // ---- per-row(lc) rescale factors for P frags ----
      float sclR0, sclR1, sclR2, sclR3, sclI0, sclI1, sclI2, sclI3;
      {
        f32x4 g = *(const f32x4*)&sM[buf][0][lc][0];
        float mt = fmaxf(fmaxf(g[0], g[1]), fmaxf(g[2], g[3]));
        float mn = fmaxf(mlcR, mt);
        mlcR = mn;
        sclR0 = __expf(g[0] - mn);
        sclR1 = __expf(g[1] - mn);
        sclR2 = __expf(g[2] - mn);
        sclR3 = __expf(g[3] - mn);
      }
      {
        f32x4 g = *(const f32x4*)&sM[buf][1][lc][0];
        float mt = fmaxf(fmaxf(g[0], g[1]), fmaxf(g[2], g[3]));
        float mn = fmaxf(mlcI, mt);
        mlcI = mn;
        sclI0 = __expf(g[0] - mn);
        sclI1 = __expf(g[1] - mn);
        sclI2 = __expf(g[2] - mn);
        sclI3 = __expf(g[3] - mn);
      }
      int h = q >> 1;  // frag at ks spans j-tile ks*2+h -> owner wave ks*2+h
      _Float16 fr0 = (_Float16)(h ? sclR1 : sclR0);
      _Float16 fr1 = (_Float16)(h ? sclR3 : sclR2);
      _Float16 fi0 = (_Float16)(h ? sclI1 : sclI0);
      _Float16 fi1 = (_Float16)(h ? sclI3 : sclI2);

      // ---- PV: A-frags from sP (rescaled), B-frags coalesced from Vpack ----
      f16x8 aPr[2], aPi[2];
      aPr[0] = *(const f16x8*)&sP[buf][0][lc][q * 8];
      aPi[0] = *(const f16x8*)&sP[buf][1][lc][q * 8];
      aPr[1] = *(const f16x8*)&sP[buf][0][lc][32 + q * 8];
      aPi[1] = *(const f16x8*)&sP[buf][1][lc][32 + q * 8];
#pragma unroll
      for (int i = 0; i < 8; ++i) {
        aPr[0][i] *= fr0; aPi[0][i] *= fi0;
        aPr[1][i] *= fr1; aPi[1][i] *= fi1;
      }

      __builtin_amdgcn_s_setprio(1);
#pragma unroll
      for (int ti = 0; ti < 5; ++ti) {
        if (ti < nt) {
          int et = t0 + ti;
          // issue V loads first, rescale VALU under their latency, then MFMA
          f16x8 bVr0, bVi0, bVr1, bVi1;
          {
            size_t vb0 = (((size_t)(b * 2 + 0) * 17 + et) * 16 + (jt * 2 + 0)) * 512;
            size_t vb0i = (((size_t)(b * 2 + 1) * 17 + et) * 16 + (jt * 2 + 0)) * 512;
            size_t vb1 = (((size_t)(b * 2 + 0) * 17 + et) * 16 + (jt * 2 + 1)) * 512;
            size_t vb1i = (((size_t)(b * 2 + 1) * 17 + et) * 16 + (jt * 2 + 1)) * 512;
            bVr0 = *(const f16x8*)(Vpack + vb0 + L * 8);
            bVi0 = *(const f16x8*)(Vpack + vb0i + L * 8);
            bVr1 = *(const f16x8*)(Vpack + vb1 + L * 8);
            bVi1 = *(const f16x8*)(Vpack + vb1i + L * 8);
          }
#pragma unroll
          for (int r = 0; r < 4; ++r) {
            accRR[ti][r] *= fac_r[r]; accRI[ti][r] *= fac_r[r];
            accIR[ti][r] *= fac_i[r]; accII[ti][r] *= fac_i[r];
          }
          accRR[ti] = __builtin_amdgcn_mfma_f32_16x16x32_f16(aPr[0], bVr0, accRR[ti], 0, 0, 0);
          accRI[ti] = __builtin_amdgcn_mfma_f32_16x16x32_f16(aPr[0], bVi0, accRI[ti], 0, 0, 0);
          accIR[ti] = __builtin_amdgcn_mfma_f32_16x16x32_f16(aPi[0], bVr0, accIR[ti], 0, 0, 0);
          accII[ti] = __builtin_amdgcn_mfma_f32_16x16x32_f16(aPi[0], bVi0, accII[ti], 0, 0, 0);
          accRR[ti] = __builtin_amdgcn_mfma_f32_16x16x32_f16(aPr[1], bVr1, accRR[ti], 0, 0, 0);
          accRI[ti] = __builtin_amdgcn_mfma_f32_16x16x32_f16(aPr[1], bVi1, accRI[ti], 0, 0, 0);
          accIR[ti] = __builtin_amdgcn_mfma_f32_16x16x32_f16(aPi[1], bVr1, accIR[ti], 0, 0, 0);
          accII[ti] = __builtin_amdgcn_mfma_f32_16x16x32_f16(aPi[1], bVi1, accII[ti], 0, 0, 0);
        }
      }
      __builtin_amdgcn_s_setprio(0);
      // no trailing barrier: next chunk writes the other sP/sM/sS buffer
    }

    // ---- finalize pass (INV_S compensates V pre-scaling) ----
#pragma unroll
    for (int r = 0; r < 4; ++r) {
      float ir = INV_S / l_r[r];
      float ii = INV_S / l_i[r];
#pragma unroll
      for (int ti = 0; ti < 5; ++ti) {
        if (ti < nt) {
          outR[ti][r] += accRR[ti][r] * ir - accII[ti][r] * ii;
          outI[ti][r] += accRI[ti][r] * ir + accIR[ti][r] * ii;
        }
      }
    }
  }

  // ---- store OXh f16 rows into LHf[.][528..1056) ----
  _Float16* obase = OXh + (size_t)(b * 512 + rt * 16) * LD16 + OXOFF;
#pragma unroll
  for (int ti = 0; ti < 5; ++ti) {
    if (ti < nt) {
      int e = (t0 + ti) * 16 + lc;
      if (e < 257) {
#pragma unroll
        for (int r = 0; r < 4; ++r) {
          _Float16* dst = obase + (size_t)(q * 4 + r) * LD16;
          dst[e] = (_Float16)outR[ti][r];
          dst[264 + e] = (_Float16)outI[ti][r];
        }
      }
    }
  }
}

// ---------------- MFMA f16 GEMM: out = OXh @ iDt ----------------
// M=32768, N=512 (8 tiles), K=528 (pad 544). A = LHf+OXOFF (f16, ld 1056).

__global__ __launch_bounds__(256) void gemm_irfft(
    const _Float16* __restrict__ LHf, const _Float16* __restrict__ iDt,
    float* __restrict__ out) {
  __shared__ __align__(16) char lds[33792];
  _Float16* As = (_Float16*)lds;              // [128][40]
  _Float16* Bs = (_Float16*)(lds + 10240);    // [64][40]
  float* CL = (float*)lds;                    // [128][66]

  int t = threadIdx.x;
  int w = t >> 6, L = t & 63, q = L >> 4, lc = L & 15;
  int row0 = blockIdx.y * 128;
  int n0 = blockIdx.x * 64;

  const f16x8 zero8 = {(_Float16)0, (_Float16)0, (_Float16)0, (_Float16)0,
                       (_Float16)0, (_Float16)0, (_Float16)0, (_Float16)0};

  f32x4 acc[2][4];
#pragma unroll
  for (int i = 0; i < 2; ++i)
#pragma unroll
    for (int j = 0; j < 4; ++j) acc[i][j] = f32x4{0.f, 0.f, 0.f, 0.f};

  for (int k0 = 0; k0 < 544; k0 += 32) {
    {
      int m = t >> 1, half = t & 1;
      int kk = k0 + half * 16;
      f16x8 h0, h1;
      if (kk < 528) {
        const _Float16* src = LHf + (size_t)(row0 + m) * LD16 + OXOFF + kk;
        h0 = *(const f16x8*)(src);
        h1 = *(const f16x8*)(src + 8);
      } else {
        h0 = zero8; h1 = zero8;
      }
      *(f16x8*)(As + m * 40 + half * 16) = h0;
      *(f16x8*)(As + m * 40 + half * 16 + 8) = h1;
    }
    {
      int row = t >> 2, ch = t & 3;
      f16x8 bv = *(const f16x8*)(iDt + (size_t)(n0 + row) * 544 + k0 + ch * 8);
      *(f16x8*)(Bs + row * 40 + ch * 8) = bv;
    }
    __syncthreads();
#pragma unroll
    for (int sub = 0; sub < 2; ++sub) {
      f16x8 af = *(const f16x8*)(As + (w * 32 + sub * 16 + lc) * 40 + q * 8);
#pragma unroll
      for (int ns = 0; ns < 4; ++ns) {
        f16x8 bf = *(const f16x8*)(Bs + (ns * 16 + lc) * 40 + q * 8);
        acc[sub][ns] = __builtin_amdgcn_mfma_f32_16x16x32_f16(af, bf, acc[sub][ns], 0, 0, 0);
      }
    }
    __syncthreads();
  }

#pragma unroll
  for (int sub = 0; sub < 2; ++sub)
#pragma unroll
    for (int ns = 0; ns < 4; ++ns)
#pragma unroll
      for (int r = 0; r < 4; ++r)
        CL[(w * 32 + sub * 16 + q * 4 + r) * 66 + ns * 16 + lc] = acc[sub][ns][r];
  __syncthreads();

#pragma unroll
  for (int rep = 0; rep < 8; ++rep) {
    int idx = rep * 256 + t;
    int row = idx >> 4;
    int c4 = idx & 15;
    f32x4 v = *(const f32x4*)(CL + row * 66 + c4 * 4);
    float4 o = {v[0], v[1], v[2], v[3]};
    *(float4*)(out + (size_t)(row0 + row) * 512 + n0 + c4 * 4) = o;
  }
}

// ---------------- launch ----------------

extern "C" void kernel_launch(void* const* d_in, const int* in_sizes, int n_in,
                              void* d_out, int out_size, void* d_ws, size_t ws_size,
                              hipStream_t stream) {
  const float* x   = (const float*)d_in[0];
  const float* l1r = (const float*)d_in[1];
  const float* l1i = (const float*)d_in[2];
  const float* h1r = (const float*)d_in[3];
  const float* h1i = (const float*)d_in[4];
  const float* lbr = (const float*)d_in[5];
  const float* lbi = (const float*)d_in[6];
  const float* hbr = (const float*)d_in[7];
  const float* hbi = (const float*)d_in[8];
  float* out = (float*)d_out;

  _Float16* ws = (_Float16*)d_ws;
  size_t off = 0;
  _Float16* LHf = ws + off;   off += (size_t)32768 * LD16;        // 69.2 MB
  _Float16* Kpack = ws + off; off += (size_t)73728 * 512;         // 75.5 MB
  _Float16* Vpack = ws + off; off += (size_t)64 * 2 * 17 * 16 * 512;  // 35.7 MB
  _Float16* Wt = ws + off;    off += (size_t)1088 * 512;          // 1.1 MB
  _Float16* iDt = ws + off;   off += (size_t)512 * 544;           // 0.6 MB

  hipMemsetAsync(LHf, 0, (size_t)32768 * LD16 * 2, stream);

  build_W<<<1088, 256, 0, stream>>>(l1r, l1i, h1r, h1i, Wt);
  build_idt<<<(512 * 544 + 255) / 256, 256, 0, stream>>>(iDt);

  gemm_main<<<dim3(17, 256), 256, 0, stream>>>(x, Wt, lbr, lbi, hbr, hbi, LHf);
  repack_K<<<73728 / 4, 256, 0, stream>>>(LHf, Kpack);
  repack_V<<<64 * 2 * 17, 256, 0, stream>>>(LHf, Vpack);
  attn_mfma3<<<2048, 256, 0, stream>>>(LHf, Kpack, Vpack, LHf);
  gemm_irfft<<<dim3(8, 256), 256, 0, stream>>>(LHf, iDt, out);
}

// Round 3
// 801.804 us; speedup vs baseline: 1.4426x; 1.0783x over previous
//
#include <hip/hip_runtime.h>
#include <math.h>

// B=64, C=512, S=512, E=257, LK=128, HK=129.
// high_x is dead code in the reference: only low_x = attn(low,low,low)+attn(low,high,low).
//
// Pipeline (all heavy math on MFMA f16):
//  1. build_W: Wt[c][n] f16 = combined rfft+projection weight (512 -> 1028), B-transposed
//  2. build_idt: iDt[n][k] f16 = irfft matrix matching OXh row layout [re264|im264]
//  3. gemm_main (MFMA f16): LHf = relu(x @ W + bias) * S_FOLD, f16 rows [lr|li|hr|hi] (264 pad)
//  4. repack_K: LHf -> Kpack in exact MFMA B-frag order (coalesced attention loads)
//  5. repack_V: LHf low -> Vpack (LDS transpose) in PV B-frag order
//  6. attn (MFMA f16 flash, DEFERRED PV): phase1 QK+local softmax (no barriers) ->
//     one barrier -> stat merge -> PV with pre-normalized A-frags (no barriers).
//     5 barriers/block total vs 17; 2 output accs instead of 4 products + out.
//  7. gemm_irfft (MFMA f16): out = OXh @ iDt
//
// ws: LHf 69.2 MB + Kpack 75.5 MB + Vpack 35.7 MB + Wt 1.1 MB + iDt 0.6 MB ~= 182 MB.

#define LD16 1056   // halves per LHf row: [lr 264 | li 264 | hr 264 | hi 264]
#define OXOFF 528   // OXh f16 output written into LHf[row][528..1056): [re 264 | im 264]

typedef __attribute__((ext_vector_type(4))) _Float16 f16x4;
typedef __attribute__((ext_vector_type(8))) _Float16 f16x8;
typedef __attribute__((ext_vector_type(4))) float f32x4;

#define S_FOLD 0.24975653f    // sqrt(1/sqrt(257))
#define INV_S  4.0039005f     // 1/S_FOLD
#define SC512  0.0441941738241592f   // 1/sqrt(512)

// ---------------- build combined rfft+projection weight, B-transposed ----------------
// Wt[c][n], c in [0,1088), n in [0,512). c>=1028 -> 0.
// c<257: low_r; 257..513: low_i; 514..770: high_r; 771..1027: high_i.

__global__ __launch_bounds__(256) void build_W(
    const float* __restrict__ l1r, const float* __restrict__ l1i,
    const float* __restrict__ h1r, const float* __restrict__ h1i,
    _Float16* __restrict__ Wt) {
  int c = blockIdx.x;
  int t = threadIdx.x;
  if (c >= 1028) {
    for (int n = t; n < 512; n += 256) Wt[(size_t)c * 512 + n] = (_Float16)0.0f;
    return;
  }
  __shared__ float Tc[512], Ts[512];
  __shared__ float wr[132], wi[132];
  for (int i = t; i < 512; i += 256) {
    float ang = (float)i * 0.0122718463030851f;  // 2*pi/512
    Tc[i] = cosf(ang);
    Ts[i] = sinf(ang);
  }
  int sub = (c >= 771) ? 3 : (c >= 514) ? 2 : (c >= 257) ? 1 : 0;
  int e = c - sub * 257;
  int Kn = (sub < 2) ? 128 : 129;
  int kb = (sub < 2) ? 0 : 128;
  if (t < Kn) {
    if (sub < 2) { wr[t] = l1r[t * 257 + e]; wi[t] = l1i[t * 257 + e]; }
    else         { wr[t] = h1r[t * 257 + e]; wi[t] = h1i[t * 257 + e]; }
  }
  __syncthreads();
  bool imag_out = (sub & 1);
  for (int n = t; n < 512; n += 256) {
    float acc = 0.f;
    for (int k = 0; k < Kn; ++k) {
      int kk = kb + k;
      int m = (n * kk) & 511;
      float Fr = Tc[m] * SC512;
      float Fi = -Ts[m] * SC512;
      if (!imag_out) acc += Fr * wr[k] - Fi * wi[k];
      else           acc += Fr * wi[k] + Fi * wr[k];
    }
    Wt[(size_t)c * 512 + n] = (_Float16)acc;
  }
}

// ---------------- build irfft matrix, B-transposed, matching OXh layout ----------------
// iDt[n][k], n in [0,512), k in [0,544). k<264: e=k cos part; 264..527: e=k-264 sin part.

__global__ __launch_bounds__(256) void build_idt(_Float16* __restrict__ iDt) {
  int idx = blockIdx.x * 256 + threadIdx.x;
  const int total = 512 * 544;
  if (idx >= total) return;
  int n = idx / 544;
  int k = idx - n * 544;
  float val = 0.f;
  if (k < 264) {
    int e = k;
    if (e <= 256) {
      float ce = (e == 0 || e == 256) ? 1.f : 2.f;
      int m = (n * e) & 511;
      val = ce * SC512 * cosf((float)m * 0.0122718463030851f);
    }
  } else if (k < 528) {
    int e = k - 264;
    if (e <= 256) {
      float ce = (e == 0 || e == 256) ? 1.f : 2.f;
      int m = (n * e) & 511;
      val = -ce * SC512 * sinf((float)m * 0.0122718463030851f);
    }
  }
  iDt[(size_t)n * 544 + k] = (_Float16)val;
}

// ---------------- MFMA f16 GEMM: LHf = relu(x @ W + bias) * S_FOLD ----------------
// M=32768, N=1028 (17 tiles of 64), K=512. A fp32 converted in staging, B = Wt f16 [c][k].
// grid (17, 256), block 256 (4 waves); tile 128(M) x 64(N), BK=32.

__global__ __launch_bounds__(256) void gemm_main(
    const float* __restrict__ X, const _Float16* __restrict__ Wt,
    const float* __restrict__ lbr, const float* __restrict__ lbi,
    const float* __restrict__ hbr, const float* __restrict__ hbi,
    _Float16* __restrict__ LHf) {
  __shared__ __align__(16) char lds[33792];
  _Float16* As = (_Float16*)lds;              // [128][40]
  _Float16* Bs = (_Float16*)(lds + 10240);    // [64][40]
  float* CL = (float*)lds;                    // [128][66]

  int t = threadIdx.x;
  int w = t >> 6, L = t & 63, q = L >> 4, lc = L & 15;
  int row0 = blockIdx.y * 128;
  int n0 = blockIdx.x * 64;

  f32x4 acc[2][4];
#pragma unroll
  for (int i = 0; i < 2; ++i)
#pragma unroll
    for (int j = 0; j < 4; ++j) acc[i][j] = f32x4{0.f, 0.f, 0.f, 0.f};

  for (int k0 = 0; k0 < 512; k0 += 32) {
    // stage A (fp32 -> f16)
    {
      int m = t >> 1, half = t & 1;
      const float* src = X + (size_t)(row0 + m) * 512 + k0 + half * 16;
      float4 a0 = *(const float4*)(src + 0);
      float4 a1 = *(const float4*)(src + 4);
      float4 a2 = *(const float4*)(src + 8);
      float4 a3 = *(const float4*)(src + 12);
      f16x8 h0 = {(_Float16)a0.x, (_Float16)a0.y, (_Float16)a0.z, (_Float16)a0.w,
                  (_Float16)a1.x, (_Float16)a1.y, (_Float16)a1.z, (_Float16)a1.w};
      f16x8 h1 = {(_Float16)a2.x, (_Float16)a2.y, (_Float16)a2.z, (_Float16)a2.w,
                  (_Float16)a3.x, (_Float16)a3.y, (_Float16)a3.z, (_Float16)a3.w};
      *(f16x8*)(As + m * 40 + half * 16) = h0;
      *(f16x8*)(As + m * 40 + half * 16 + 8) = h1;
    }
    // stage B
    {
      int row = t >> 2, ch = t & 3;
      f16x8 bv = *(const f16x8*)(Wt + (size_t)(n0 + row) * 512 + k0 + ch * 8);
      *(f16x8*)(Bs + row * 40 + ch * 8) = bv;
    }
    __syncthreads();
#pragma unroll
    for (int sub = 0; sub < 2; ++sub) {
      f16x8 af = *(const f16x8*)(As + (w * 32 + sub * 16 + lc) * 40 + q * 8);
#pragma unroll
      for (int ns = 0; ns < 4; ++ns) {
        f16x8 bf = *(const f16x8*)(Bs + (ns * 16 + lc) * 40 + q * 8);
        acc[sub][ns] = __builtin_amdgcn_mfma_f32_16x16x32_f16(af, bf, acc[sub][ns], 0, 0, 0);
      }
    }
    __syncthreads();
  }

  // epilogue: reorder via LDS, then bias+relu+scale+f16 pack into LHf
#pragma unroll
  for (int sub = 0; sub < 2; ++sub)
#pragma unroll
    for (int ns = 0; ns < 4; ++ns)
#pragma unroll
      for (int r = 0; r < 4; ++r)
        CL[(w * 32 + sub * 16 + q * 4 + r) * 66 + ns * 16 + lc] = acc[sub][ns][r];
  __syncthreads();

#pragma unroll
  for (int rep = 0; rep < 8; ++rep) {
    int idx = rep * 256 + t;
    int row = idx >> 4;
    int c4 = idx & 15;
    f32x4 v = *(const f32x4*)(CL + row * 66 + c4 * 4);
    int rowg = row0 + row;
#pragma unroll
    for (int jj = 0; jj < 4; ++jj) {
      int c = n0 + c4 * 4 + jj;
      if (c < 1028) {
        int sub = (c >= 771) ? 3 : (c >= 514) ? 2 : (c >= 257) ? 1 : 0;
        int e = c - sub * 257;
        float bv = (sub == 0) ? lbr[e] : (sub == 1) ? lbi[e] : (sub == 2) ? hbr[e] : hbi[e];
        float val = fmaxf(v[jj] + bv, 0.f) * S_FOLD;
        LHf[(size_t)rowg * LD16 + sub * 264 + e] = (_Float16)val;
      }
    }
  }
}

// ---------------- repack K into MFMA B-frag-linear order ----------------
// Kpack chunk wc = (((b*2+pass)*2+comp)*32 + jt)*9 + ec ; chunk = [64 lanes][8 halves].
// Lane L: j = jt*16 + (L&15), e = ec*32 + (L>>4)*8 + i.

__global__ __launch_bounds__(256) void repack_K(
    const _Float16* __restrict__ LHf, _Float16* __restrict__ Kpack) {
  int t = threadIdx.x;
  int w = t >> 6, L = t & 63, q = L >> 4, lc = L & 15;
  int wc = blockIdx.x * 4 + w;
  int ec = wc % 9;
  int tmp = wc / 9;
  int jt = tmp & 31; tmp >>= 5;
  int comp = tmp & 1; tmp >>= 1;
  int pass = tmp & 1;
  int b = tmp >> 1;
  f16x8 v;
  if (ec == 8 && q > 0) {
    v = f16x8{(_Float16)0, (_Float16)0, (_Float16)0, (_Float16)0,
              (_Float16)0, (_Float16)0, (_Float16)0, (_Float16)0};
  } else {
    v = *(const f16x8*)(LHf + (size_t)(b * 512 + jt * 16 + lc) * LD16 +
                        pass * 528 + comp * 264 + ec * 32 + q * 8);
  }
  *(f16x8*)(Kpack + (size_t)wc * 512 + L * 8) = v;
}

// ---------------- repack V (low) into PV B-frag order via LDS transpose ----------------
// Vpack[b][comp][et(17)][ks(16)][64 lanes][8]; lane L: e = et*16+(L&15), j = ks*32+(L>>4)*8+i.

__global__ __launch_bounds__(256) void repack_V(
    const _Float16* __restrict__ LHf, _Float16* __restrict__ Vpack) {
  int bid = blockIdx.x;
  int et = bid % 17;
  int tmp = bid / 17;
  int comp = tmp & 1;
  int b = tmp >> 1;
  int t = threadIdx.x;
  __shared__ __align__(16) _Float16 tile[512 * 16];

  const f16x8 zero8 = {(_Float16)0, (_Float16)0, (_Float16)0, (_Float16)0,
                       (_Float16)0, (_Float16)0, (_Float16)0, (_Float16)0};
  for (int j = t; j < 512; j += 256) {
    const _Float16* src = LHf + (size_t)(b * 512 + j) * LD16 + comp * 264 + et * 16;
    f16x8 v0, v1;
    if (et < 16) {
      v0 = *(const f16x8*)(src);
      v1 = *(const f16x8*)(src + 8);
    } else {  // e = 256..271: only first 8 within sub-block (256 real, 257..263 zero)
      v0 = *(const f16x8*)(src);
      v1 = zero8;
    }
    *(f16x8*)(tile + j * 16) = v0;
    *(f16x8*)(tile + j * 16 + 8) = v1;
  }
  __syncthreads();

#pragma unroll
  for (int it = 0; it < 4; ++it) {
    int c2 = it * 256 + t;
    int ks = c2 >> 6;
    int L2 = c2 & 63;
    int q2 = L2 >> 4, lc2 = L2 & 15;
    f16x8 v;
#pragma unroll
    for (int i = 0; i < 8; ++i) v[i] = tile[(ks * 32 + q2 * 8 + i) * 16 + lc2];
    *(f16x8*)(Vpack + ((((size_t)(b * 2 + comp) * 17 + et) * 16 + ks) * 512) + L2 * 8) = v;
  }
}

// ---------------- DPP 16-lane reductions (VALU pipe, no DS latency) ----------------

template <int CTRL>
__device__ __forceinline__ float dpp_f32(float x) {
  return __int_as_float(
      __builtin_amdgcn_update_dpp(0, __float_as_int(x), CTRL, 0xF, 0xF, true));
}

__device__ __forceinline__ float red_max16(float x) {
  x = fmaxf(x, dpp_f32<0xB1>(x));
  x = fmaxf(x, dpp_f32<0x4E>(x));
  x = fmaxf(x, dpp_f32<0x141>(x));
  x = fmaxf(x, dpp_f32<0x140>(x));
  return x;
}

__device__ __forceinline__ float red_sum16(float x) {
  x += dpp_f32<0xB1>(x);
  x += dpp_f32<0x4E>(x);
  x += dpp_f32<0x141>(x);
  x += dpp_f32<0x140>(x);
  return x;
}

// ---------------- MFMA f16 flash attention, DEFERRED PV ----------------
// Per pass:
//  phase1 (NO barriers): 8 chunks of {QK MFMA, DPP local softmax}; u=exp(v-mloc) into
//    sPall, (mloc,sumloc) per 16-j tile into sMall/sSall. Per-wave regions disjoint.
//  barrier; per-lane merge for row lc: m_final, l, g_base = INV_S/l.
//  PV (NO barriers): A-frags pre-normalized (u * exp(mloc-m_final) * g_base), the 4
//    complex products fold into 2 accumulators (sign folded into imag A-frag).
//  barrier (sPall reuse by next pass).
// accR/accI accumulate across both passes and store directly (no epilogue scaling).

__global__ __launch_bounds__(256, 2) void attn_mfma3(
    const _Float16* __restrict__ LHf, const _Float16* __restrict__ Kpack,
    const _Float16* __restrict__ Vpack, _Float16* __restrict__ OXh) {
  int bid = blockIdx.x;
  int xcd = bid & 7;
  int ix = bid >> 3;
  int rt = ix & 31;
  int b = xcd + 8 * (ix >> 5);
  int t = threadIdx.x;
  int w = t >> 6, L = t & 63, q = L >> 4, lc = L & 15;

  __shared__ __align__(16) _Float16 sQ[2][16][296];   // 18.9 KB
  __shared__ __align__(16) _Float16 sPall[2][16][520]; // 33.3 KB: u for all 512 j
  __shared__ __align__(16) float sMall[2][16][32];    // local max per 16-j tile
  __shared__ __align__(16) float sSall[2][16][32];    // local sum per 16-j tile

  const f16x8 zero8 = {(_Float16)0, (_Float16)0, (_Float16)0, (_Float16)0,
                       (_Float16)0, (_Float16)0, (_Float16)0, (_Float16)0};

  // fill sQ (A-frag layout: row=lc, k=ec*32+q*8+i), 18 frag-groups over 4 waves
  {
    const _Float16* qbase = LHf + (size_t)(b * 512 + rt * 16 + lc) * LD16;
    for (int g = w; g < 18; g += 4) {
      int comp = g / 9, ec = g - (comp * 9);
      f16x8 v = (ec == 8 && q != 0)
                    ? zero8
                    : *(const f16x8*)(qbase + comp * 264 + ec * 32 + q * 8);
      *(f16x8*)(&sQ[comp][lc][ec * 32 + q * 8]) = v;
    }
  }
  __syncthreads();

  int t0 = (w == 0) ? 0 : (4 * w + 1);   // et tiles {0..4},{5..8},{9..12},{13..16}
  int nt = (w == 0) ? 5 : 4;
  int h = q >> 1;

  f32x4 accR[5], accI[5];  // final normalized outputs, accumulated across passes
#pragma unroll
  for (int i = 0; i < 5; ++i) {
    accR[i] = f32x4{0.f, 0.f, 0.f, 0.f};
    accI[i] = f32x4{0.f, 0.f, 0.f, 0.f};
  }

  for (int pass = 0; pass < 2; ++pass) {
    // ================= phase 1: QK + local softmax, no barriers =================
    for (int jt = 0; jt < 8; ++jt) {
      size_t kb0 = ((((size_t)(b * 2 + pass) * 2 + 0) * 32 + (jt * 4 + w)) * 9) * 512;
      size_t kb1 = ((((size_t)(b * 2 + pass) * 2 + 1) * 32 + (jt * 4 + w)) * 9) * 512;
      f32x4 sRR = f32x4{0.f, 0.f, 0.f, 0.f};
      f32x4 sII = f32x4{0.f, 0.f, 0.f, 0.f};
      f32x4 sRI = f32x4{0.f, 0.f, 0.f, 0.f};
      f32x4 sIR = f32x4{0.f, 0.f, 0.f, 0.f};
      __builtin_amdgcn_s_setprio(1);
#pragma unroll
      for (int ec = 0; ec < 9; ++ec) {
        f16x8 bKr = *(const f16x8*)(Kpack + kb0 + (size_t)ec * 512 + L * 8);
        f16x8 bKi = *(const f16x8*)(Kpack + kb1 + (size_t)ec * 512 + L * 8);
        f16x8 q0 = *(const f16x8*)(&sQ[0][lc][ec * 32 + q * 8]);
        f16x8 q1 = *(const f16x8*)(&sQ[1][lc][ec * 32 + q * 8]);
        sRR = __builtin_amdgcn_mfma_f32_16x16x32_f16(q0, bKr, sRR, 0, 0, 0);
        sII = __builtin_amdgcn_mfma_f32_16x16x32_f16(q1, bKi, sII, 0, 0, 0);
        sRI = __builtin_amdgcn_mfma_f32_16x16x32_f16(q0, bKi, sRI, 0, 0, 0);
        sIR = __builtin_amdgcn_mfma_f32_16x16x32_f16(q1, bKr, sIR, 0, 0, 0);
      }
      __builtin_amdgcn_s_setprio(0);

      int wcol = (jt * 4 + w) * 16 + lc;
      int jtile = jt * 4 + w;
#pragma unroll
      for (int r = 0; r < 4; ++r) {
        float vr = sRR[r] - sII[r];
        float vi = sRI[r] + sIR[r];
        float mlr = red_max16(vr);
        float mli = red_max16(vi);
        float ur = __expf(vr - mlr);
        float ui = __expf(vi - mli);
        int row = q * 4 + r;
        sPall[0][row][wcol] = (_Float16)ur;
        sPall[1][row][wcol] = (_Float16)ui;
        float sr = red_sum16(ur);
        float si = red_sum16(ui);
        if (lc == 0) {
          sMall[0][row][jtile] = mlr;
          sSall[0][row][jtile] = sr;
          sMall[1][row][jtile] = mli;
          sSall[1][row][jtile] = si;
        }
      }
    }
    __syncthreads();  // P + stats published

    // ================= stat merge for row lc =================
    float mfR = -3.0e38f, mfI = -3.0e38f;
#pragma unroll
    for (int j4 = 0; j4 < 8; ++j4) {
      f32x4 a = *(const f32x4*)&sMall[0][lc][j4 * 4];
      f32x4 c = *(const f32x4*)&sMall[1][lc][j4 * 4];
      mfR = fmaxf(mfR, fmaxf(fmaxf(a[0], a[1]), fmaxf(a[2], a[3])));
      mfI = fmaxf(mfI, fmaxf(fmaxf(c[0], c[1]), fmaxf(c[2], c[3])));
    }
    float lR = 0.f, lI = 0.f;
#pragma unroll
    for (int j4 = 0; j4 < 8; ++j4) {
      f32x4 mr = *(const f32x4*)&sMall[0][lc][j4 * 4];
      f32x4 sr = *(const f32x4*)&sSall[0][lc][j4 * 4];
      f32x4 mi = *(const f32x4*)&sMall[1][lc][j4 * 4];
      f32x4 si = *(const f32x4*)&sSall[1][lc][j4 * 4];
#pragma unroll
      for (int kk = 0; kk < 4; ++kk) {
        lR += sr[kk] * __expf(mr[kk] - mfR);
        lI += si[kk] * __expf(mi[kk] - mfI);
      }
    }
    float gRb = INV_S / lR;
    float gIb = INV_S / lI;

    // ================= PV: pre-normalized A-frags, 2 accs, no barriers =========
    for (int ks = 0; ks < 16; ++ks) {
      int jtA = ks * 2 + h;
      float gR = __expf(sMall[0][lc][jtA] - mfR) * gRb;
      float gI = __expf(sMall[1][lc][jtA] - mfI) * gIb;
      f16x8 uR = *(const f16x8*)&sPall[0][lc][ks * 32 + q * 8];
      f16x8 uI = *(const f16x8*)&sPall[1][lc][ks * 32 + q * 8];
      _Float16 hR = (_Float16)gR;
      _Float16 hI = (_Float16)gI;
      _Float16 hmI = (_Float16)(-gI);
      f16x8 aR, aI, amI;
#pragma unroll
      for (int i = 0; i < 8; ++i) {
        aR[i] = uR[i] * hR;
        aI[i] = uI[i] * hI;
        amI[i] = uI[i] * hmI;
      }
      __builtin_amdgcn_s_setprio(1);
#pragma unroll
      for (int ti = 0; ti < 5; ++ti) {
        if (ti < nt) {
          int et = t0 + ti;
          size_t vb = (((size_t)(b * 2 + 0) * 17 + et) * 16 + ks) * 512;
          size_t vb2 = (((size_t)(b * 2 + 1) * 17 + et) * 16 + ks) * 512;
          f16x8 bVr = *(const f16x8*)(Vpack + vb + L * 8);
          f16x8 bVi = *(const f16x8*)(Vpack + vb2 + L * 8);
          accR[ti] = __builtin_amdgcn_mfma_f32_16x16x32_f16(aR, bVr, accR[ti], 0, 0, 0);
          accR[ti] = __builtin_amdgcn_mfma_f32_16x16x32_f16(amI, bVi, accR[ti], 0, 0, 0);
          accI[ti] = __builtin_amdgcn_mfma_f32_16x16x32_f16(aR, bVi, accI[ti], 0, 0, 0);
          accI[ti] = __builtin_amdgcn_mfma_f32_16x16x32_f16(aI, bVr, accI[ti], 0, 0, 0);
        }
      }
      __builtin_amdgcn_s_setprio(0);
    }
    __syncthreads();  // sPall/sMall/sSall reused by next pass's phase 1
  }

  // ---- store OXh f16 rows into LHf[.][528..1056) ----
  _Float16* obase = OXh + (size_t)(b * 512 + rt * 16) * LD16 + OXOFF;
#pragma unroll
  for (int ti = 0; ti < 5; ++ti) {
    if (ti < nt) {
      int e = (t0 + ti) * 16 + lc;
      if (e < 257) {
#pragma unroll
        for (int r = 0; r < 4; ++r) {
          _Float16* dst = obase + (size_t)(q * 4 + r) * LD16;
          dst[e] = (_Float16)accR[ti][r];
          dst[264 + e] = (_Float16)accI[ti][r];
        }
      }
    }
  }
}

// ---------------- MFMA f16 GEMM: out = OXh @ iDt ----------------
// M=32768, N=512 (8 tiles), K=528 (pad 544). A = LHf+OXOFF (f16, ld 1056).

__global__ __launch_bounds__(256) void gemm_irfft(
    const _Float16* __restrict__ LHf, const _Float16* __restrict__ iDt,
    float* __restrict__ out) {
  __shared__ __align__(16) char lds[33792];
  _Float16* As = (_Float16*)lds;              // [128][40]
  _Float16* Bs = (_Float16*)(lds + 10240);    // [64][40]
  float* CL = (float*)lds;                    // [128][66]

  int t = threadIdx.x;
  int w = t >> 6, L = t & 63, q = L >> 4, lc = L & 15;
  int row0 = blockIdx.y * 128;
  int n0 = blockIdx.x * 64;

  const f16x8 zero8 = {(_Float16)0, (_Float16)0, (_Float16)0, (_Float16)0,
                       (_Float16)0, (_Float16)0, (_Float16)0, (_Float16)0};

  f32x4 acc[2][4];
#pragma unroll
  for (int i = 0; i < 2; ++i)
#pragma unroll
    for (int j = 0; j < 4; ++j) acc[i][j] = f32x4{0.f, 0.f, 0.f, 0.f};

  for (int k0 = 0; k0 < 544; k0 += 32) {
    {
      int m = t >> 1, half = t & 1;
      int kk = k0 + half * 16;
      f16x8 h0, h1;
      if (kk < 528) {
        const _Float16* src = LHf + (size_t)(row0 + m) * LD16 + OXOFF + kk;
        h0 = *(const f16x8*)(src);
        h1 = *(const f16x8*)(src + 8);
      } else {
        h0 = zero8; h1 = zero8;
      }
      *(f16x8*)(As + m * 40 + half * 16) = h0;
      *(f16x8*)(As + m * 40 + half * 16 + 8) = h1;
    }
    {
      int row = t >> 2, ch = t & 3;
      f16x8 bv = *(const f16x8*)(iDt + (size_t)(n0 + row) * 544 + k0 + ch * 8);
      *(f16x8*)(Bs + row * 40 + ch * 8) = bv;
    }
    __syncthreads();
#pragma unroll
    for (int sub = 0; sub < 2; ++sub) {
      f16x8 af = *(const f16x8*)(As + (w * 32 + sub * 16 + lc) * 40 + q * 8);
#pragma unroll
      for (int ns = 0; ns < 4; ++ns) {
        f16x8 bf = *(const f16x8*)(Bs + (ns * 16 + lc) * 40 + q * 8);
        acc[sub][ns] = __builtin_amdgcn_mfma_f32_16x16x32_f16(af, bf, acc[sub][ns], 0, 0, 0);
      }
    }
    __syncthreads();
  }

#pragma unroll
  for (int sub = 0; sub < 2; ++sub)
#pragma unroll
    for (int ns = 0; ns < 4; ++ns)
#pragma unroll
      for (int r = 0; r < 4; ++r)
        CL[(w * 32 + sub * 16 + q * 4 + r) * 66 + ns * 16 + lc] = acc[sub][ns][r];
  __syncthreads();

#pragma unroll
  for (int rep = 0; rep < 8; ++rep) {
    int idx = rep * 256 + t;
    int row = idx >> 4;
    int c4 = idx & 15;
    f32x4 v = *(const f32x4*)(CL + row * 66 + c4 * 4);
    float4 o = {v[0], v[1], v[2], v[3]};
    *(float4*)(out + (size_t)(row0 + row) * 512 + n0 + c4 * 4) = o;
  }
}

// ---------------- launch ----------------

extern "C" void kernel_launch(void* const* d_in, const int* in_sizes, int n_in,
                              void* d_out, int out_size, void* d_ws, size_t ws_size,
                              hipStream_t stream) {
  const float* x   = (const float*)d_in[0];
  const float* l1r = (const float*)d_in[1];
  const float* l1i = (const float*)d_in[2];
  const float* h1r = (const float*)d_in[3];
  const float* h1i = (const float*)d_in[4];
  const float* lbr = (const float*)d_in[5];
  const float* lbi = (const float*)d_in[6];
  const float* hbr = (const float*)d_in[7];
  const float* hbi = (const float*)d_in[8];
  float* out = (float*)d_out;

  _Float16* ws = (_Float16*)d_ws;
  size_t off = 0;
  _Float16* LHf = ws + off;   off += (size_t)32768 * LD16;        // 69.2 MB
  _Float16* Kpack = ws + off; off += (size_t)73728 * 512;         // 75.5 MB
  _Float16* Vpack = ws + off; off += (size_t)64 * 2 * 17 * 16 * 512;  // 35.7 MB
  _Float16* Wt = ws + off;    off += (size_t)1088 * 512;          // 1.1 MB
  _Float16* iDt = ws + off;   off += (size_t)512 * 544;           // 0.6 MB

  hipMemsetAsync(LHf, 0, (size_t)32768 * LD16 * 2, stream);

  build_W<<<1088, 256, 0, stream>>>(l1r, l1i, h1r, h1i, Wt);
  build_idt<<<(512 * 544 + 255) / 256, 256, 0, stream>>>(iDt);

  gemm_main<<<dim3(17, 256), 256, 0, stream>>>(x, Wt, lbr, lbi, hbr, hbi, LHf);
  repack_K<<<73728 / 4, 256, 0, stream>>>(LHf, Kpack);
  repack_V<<<64 * 2 * 17, 256, 0, stream>>>(LHf, Vpack);
  attn_mfma3<<<2048, 256, 0, stream>>>(LHf, Kpack, Vpack, LHf);
  gemm_irfft<<<dim3(8, 256), 256, 0, stream>>>(LHf, iDt, out);
}